// Round 1
// 118.620 us; speedup vs baseline: 1.0075x; 1.0075x over previous
//
#include <hip/hip_runtime.h>

// UNet_86406152061381: pixel-sampled self-attention, fp32 in/out, C=5.
// R11 = R10 + software-pipelined k2:
//   * K/V prefetched one iter ahead into ping-pong register sets (kills the
//     per-iter vmcnt(0) stall: loads now have ~1 full body before first use)
//   * PV MFMA deferred one iter: body i does E(i)->exp->pack->write P(i) and
//     consumes P(i-1)/V(i-1) -- the ds_write->ds_read round trip gets ~160cy
//     of independent work in between instead of back-to-back lgkmcnt(0)
//   * P tile double-buffered in LDS (parity ping-pong, 16 KB) so reads and
//     writes never alias within a body
//   * __launch_bounds__(256,4) pins the 65..128-VGPR / 4-waves-per-SIMD band
// MFMA flash k2: E' = K.Q^T via mfma_f32_16x16x32_f16 (bias in C), exp2 on
// VALU, P f16 via per-wave LDS, O = P.V via MFMA, l = ones-channel 5 of V.

constexpr int HWC = 256 * 256;   // 65536
constexpr int Bc  = 4;
constexpr int Nq  = 2048;
constexpr int Wc  = 256;

constexpr int TPB   = 40;            // padded 16-q tiles per b (cb<=640 proven)
constexpr int SPLIT = 16;            // s-chunks; chunk = 4096 s; wave = 1024 s

constexpr float LOG2E = 1.4426950408889634f;
constexpr float BIAS2 = -14.0f * LOG2E;   // fixed softmax shift, base-2 domain
                                          // (-14: f16-P window, see R8 note)

// workspace layout (byte offsets, all 16B-aligned); total ~7.5 MB
constexpr size_t K8_BYTES  = (size_t)Bc * HWC * 8 * 2;   // f16[Bc][HWC][8]
constexpr size_t VT_BYTES  = (size_t)Bc * 5 * HWC * 2;   // f16[Bc][5][HWC]
constexpr size_t QP_BYTES  = (size_t)Nq * 8 * 2;         // f16[Nq][8]
constexpr size_t PART_BYTES = (size_t)SPLIT * Nq * 6 * 4;
constexpr size_t K8_OFF   = 0;
constexpr size_t VT_OFF   = K8_OFF + K8_BYTES;
constexpr size_t QP16_OFF = VT_OFF + VT_BYTES;
constexpr size_t PART_OFF = QP16_OFF + QP_BYTES;
constexpr size_t PERM_OFF = PART_OFF + PART_BYTES;       // int[Bc][Nq]
constexpr size_t CNT_OFF  = PERM_OFF + (size_t)Bc * Nq * 4;  // int[Bc]

typedef __attribute__((ext_vector_type(8))) _Float16 f16x8;
typedef __attribute__((ext_vector_type(4))) float f32x4;
union FU { uint4 u; f16x8 h; };

#if defined(__has_builtin)
#if __has_builtin(__builtin_amdgcn_exp2f)
#define EXP2F(x) __builtin_amdgcn_exp2f(x)
#endif
#endif
#ifndef EXP2F
#define EXP2F(x) exp2f(x)
#endif

__device__ inline unsigned pack2(float a, float b) {
  typedef __attribute__((ext_vector_type(2))) __fp16 fp16x2;
  union { fp16x2 h; unsigned u; } r;
  r.h = __builtin_amdgcn_cvt_pkrtz(a, b);
  return r.u;
}

// blocks 0..1023: K/V staging (f16) + y<-x copy.
// blocks 1024..1031: q_pix (scaled by LOG2E) -> f16 rows.
// block 1032: bucket queries by b (perm + cnt).
__global__ __launch_bounds__(256) void k1_prep(
    const float* __restrict__ x,
    const float* __restrict__ Wq, const float* __restrict__ bq,
    const float* __restrict__ Wk, const float* __restrict__ bk,
    const float* __restrict__ Wv, const float* __restrict__ bv,
    const int* __restrict__ idx_b, const int* __restrict__ idx_h,
    const int* __restrict__ idx_w,
    float* __restrict__ y, char* __restrict__ wsb) {
  const int tid = threadIdx.x;
  _Float16* K8   = (_Float16*)(wsb + K8_OFF);
  _Float16* VT   = (_Float16*)(wsb + VT_OFF);
  _Float16* QP16 = (_Float16*)(wsb + QP16_OFF);
  if (blockIdx.x >= 1024) {
    if (blockIdx.x == 1032) {
      __shared__ int lcnt[Bc];
      if (tid < Bc) lcnt[tid] = 0;
      __syncthreads();
      int* perm = (int*)(wsb + PERM_OFF);
#pragma unroll
      for (int qi = 0; qi < 8; ++qi) {
        const int n = qi * 256 + tid;            // Nq = 8*256 exactly
        const int b = idx_b[n];
        const int pos = atomicAdd(&lcnt[b], 1);  // order irrelevant
        perm[b * Nq + pos] = n;
      }
      __syncthreads();
      if (tid < Bc) ((int*)(wsb + CNT_OFF))[tid] = lcnt[tid];
      return;
    }
    // ---- query part: 8 blocks x 256 queries
    const int n = (blockIdx.x - 1024) * 256 + tid;
    const int b = idx_b[n];
    const int s = idx_h[n] * Wc + idx_w[n];
    float xv[5];
#pragma unroll
    for (int c = 0; c < 5; ++c) xv[c] = x[(size_t)(b * 5 + c) * HWC + s];
    float q[5];
#pragma unroll
    for (int o = 0; o < 5; ++o) {
      float t = bq[o];
#pragma unroll
      for (int c = 0; c < 5; ++c) t = fmaf(Wq[o * 5 + c], xv[c], t);
      q[o] = t * LOG2E;
    }
    uint4 row;
    row.x = pack2(q[0], q[1]);
    row.y = pack2(q[2], q[3]);
    row.z = pack2(q[4], 0.f);
    row.w = 0u;
    *(uint4*)(QP16 + (size_t)n * 8) = row;
    return;
  }
  // ---- staging: 1 pixel/thread
  const int gid = blockIdx.x * 256 + tid;      // 0..262143
  const int b   = gid >> 16;
  const int s   = gid & (HWC - 1);
  float xv[5];
#pragma unroll
  for (int c = 0; c < 5; ++c) {
    const size_t off = (size_t)(b * 5 + c) * HWC + s;
    xv[c] = x[off];
    y[off] = xv[c];
  }
  float kk[5], vv[5];
#pragma unroll
  for (int o = 0; o < 5; ++o) {
    kk[o] = bk[o];
    vv[o] = bv[o];
#pragma unroll
    for (int c = 0; c < 5; ++c) {
      kk[o] = fmaf(Wk[o * 5 + c], xv[c], kk[o]);
      vv[o] = fmaf(Wv[o * 5 + c], xv[c], vv[o]);
    }
  }
  uint4 krow;
  krow.x = pack2(kk[0], kk[1]);
  krow.y = pack2(kk[2], kk[3]);
  krow.z = pack2(kk[4], 0.f);
  krow.w = 0u;
  *(uint4*)(K8 + (size_t)(b * HWC + s) * 8) = krow;
#pragma unroll
  for (int c = 0; c < 5; ++c)
    VT[(size_t)(b * 5 + c) * HWC + s] = (_Float16)vv[c];
}

// grid (SPLIT=16, Bc*TPB=160): blockIdx.x = chunk, blockIdx.y = q-tile.
// 4 waves/block, each wave owns 1024 s of the chunk (16 iters).
//
// BODY(it): E-MFMA(cur K) -> [PV of it-1: ds_read prev-parity P, MFMA with
// other-set V] -> [prefetch it+1 K/V into other set] -> exp/pack -> ds_write
// cur-parity P. Other set's V is consumed by PV *before* the prefetch
// overwrites it; P parity ping-pong means reads/writes never alias in-body.
#define BODY(KC0, KC1, KC2, KC3, KN0, KN1, KN2, KN3, VN0, VN1,                \
             NBASE, DOPV, DOLOAD, RPW, WPW)                                   \
  do {                                                                        \
    f32x4 e0 = __builtin_amdgcn_mfma_f32_16x16x32_f16(KC0.h, qf.h, bias, 0, 0, 0); \
    f32x4 e1 = __builtin_amdgcn_mfma_f32_16x16x32_f16(KC1.h, qf.h, bias, 0, 0, 0); \
    f32x4 e2 = __builtin_amdgcn_mfma_f32_16x16x32_f16(KC2.h, qf.h, bias, 0, 0, 0); \
    f32x4 e3 = __builtin_amdgcn_mfma_f32_16x16x32_f16(KC3.h, qf.h, bias, 0, 0, 0); \
    if (DOPV) {                                                               \
      FU pa0, pa1;                                                            \
      pa0.h = *(const f16x8*)((RPW) + roff0);                                 \
      pa1.h = *(const f16x8*)((RPW) + roff1);                                 \
      oacc = __builtin_amdgcn_mfma_f32_16x16x32_f16(pa0.h, VN0.h, oacc, 0, 0, 0); \
      oacc = __builtin_amdgcn_mfma_f32_16x16x32_f16(pa1.h, VN1.h, oacc, 0, 0, 0); \
    }                                                                         \
    if (DOLOAD) {                                                             \
      if (quad == 0) {                                                        \
        KN0.u = *(const uint4*)(K8b + (size_t)((NBASE) +  0 + l15) * 8);      \
        KN1.u = *(const uint4*)(K8b + (size_t)((NBASE) + 16 + l15) * 8);      \
        KN2.u = *(const uint4*)(K8b + (size_t)((NBASE) + 32 + l15) * 8);      \
        KN3.u = *(const uint4*)(K8b + (size_t)((NBASE) + 48 + l15) * 8);      \
      }                                                                       \
      if (l15 < 5) {                                                          \
        VN0.u = *(const uint4*)(vplane + (NBASE) +  0 + 8 * quad);            \
        VN1.u = *(const uint4*)(vplane + (NBASE) + 32 + 8 * quad);            \
      }                                                                       \
    }                                                                         \
    uint2 w0, w1, w2, w3;                                                     \
    w0.x = pack2(EXP2F(e0.x), EXP2F(e0.y)); w0.y = pack2(EXP2F(e0.z), EXP2F(e0.w)); \
    w1.x = pack2(EXP2F(e1.x), EXP2F(e1.y)); w1.y = pack2(EXP2F(e1.z), EXP2F(e1.w)); \
    w2.x = pack2(EXP2F(e2.x), EXP2F(e2.y)); w2.y = pack2(EXP2F(e2.z), EXP2F(e2.w)); \
    w3.x = pack2(EXP2F(e3.x), EXP2F(e3.y)); w3.y = pack2(EXP2F(e3.z), EXP2F(e3.w)); \
    *(uint2*)((WPW) + woff0) = w0;                                            \
    *(uint2*)((WPW) + woff1) = w1;                                            \
    *(uint2*)((WPW) + woff2) = w2;                                            \
    *(uint2*)((WPW) + woff3) = w3;                                            \
  } while (0)

__global__ __launch_bounds__(256, 4) void k2_attn(char* __restrict__ wsb) {
  const int chunk = blockIdx.x;
  const int tile  = blockIdx.y;
  const int bb    = tile / TPB;
  const int tt    = tile % TPB;
  const int cb    = ((const int*)(wsb + CNT_OFF))[bb];
  const int j0    = tt * 16;
  if (j0 >= cb) return;                   // padding tile: whole block exits
  const int* perm = (const int*)(wsb + PERM_OFF) + bb * Nq;

  const int tid  = threadIdx.x;
  const int wv   = tid >> 6;
  const int lane = tid & 63;
  const int quad = lane >> 4;
  const int l15  = lane & 15;

  // P tile, double-buffered by iteration parity: [wave][parity][q=16][64].
  // Row = 64 halves (128 B, 16B-aligned). 8-byte group g of row l15 stored
  // at g ^ (2*(l15&7)): b64 writes / b128 reads stay 16B-aligned and
  // bank-conflict-free (see R10 note).
  __shared__ _Float16 Pbuf[4][2][16][64];
  __shared__ float    Ored[4][16][6];

  const _Float16* K8b  = (const _Float16*)(wsb + K8_OFF) + (size_t)bb * HWC * 8;
  const _Float16* Vtb  = (const _Float16*)(wsb + VT_OFF) + (size_t)bb * 5 * HWC;
  const _Float16* QP16 = (const _Float16*)(wsb + QP16_OFF);

  _Float16* PwE = &Pbuf[wv][0][0][0];     // even-iteration parity
  _Float16* PwO = &Pbuf[wv][1][0][0];     // odd-iteration parity
  const int swzg = 2 * (l15 & 7);          // group-unit swizzle for this row
  const int rowb = l15 << 6;               // row base in halves
  const int woff0 = rowb + (((0 * 4 + quad) ^ swzg) << 2);
  const int woff1 = rowb + (((1 * 4 + quad) ^ swzg) << 2);
  const int woff2 = rowb + (((2 * 4 + quad) ^ swzg) << 2);
  const int woff3 = rowb + (((3 * 4 + quad) ^ swzg) << 2);
  const int roff0 = rowb + (((0 + 2 * quad) ^ swzg) << 2);
  const int roff1 = rowb + (((8 + 2 * quad) ^ swzg) << 2);

  // Q B-fragment (constant): quad0 lanes hold Q[q=l15][c=0..7], rest 0
  FU qf; qf.u = make_uint4(0u, 0u, 0u, 0u);
  {
    const int jq = j0 + l15;
    if (quad == 0) {
      const int n = (jq < cb) ? perm[jq] : 0;   // invalid cols discarded at write
      qf.u = *(const uint4*)(QP16 + (size_t)n * 8);
    }
  }
  // V B-fragments (ping-pong sets A/B): ch=l15<5 loaded per iter;
  // ch==5 = ones (denominator); other lanes 0 (init survives masked loads)
  FU vA0, vA1, vB0, vB1;
  {
    const unsigned ones = (l15 == 5) ? 0x3C003C00u : 0u;
    vA0.u = make_uint4(ones, ones, ones, ones);
    vA1.u = vA0.u; vB0.u = vA0.u; vB1.u = vA0.u;
  }
  // K A-fragments (ping-pong sets A/B): only quad0 lanes ever loaded
  FU kA0, kA1, kA2, kA3, kB0, kB1, kB2, kB3;
  kA0.u = make_uint4(0u, 0u, 0u, 0u);
  kA1.u = kA0.u; kA2.u = kA0.u; kA3.u = kA0.u;
  kB0.u = kA0.u; kB1.u = kA0.u; kB2.u = kA0.u; kB3.u = kA0.u;

  const f32x4 bias = {BIAS2, BIAS2, BIAS2, BIAS2};
  f32x4 oacc = {0.f, 0.f, 0.f, 0.f};

  const _Float16* vplane = Vtb + (size_t)l15 * HWC;   // valid when l15<5

  const int s0 = chunk * (HWC / SPLIT) + wv * (HWC / SPLIT / 4);

  // prologue: load it=0 into set A
  if (quad == 0) {
    kA0.u = *(const uint4*)(K8b + (size_t)(s0 +  0 + l15) * 8);
    kA1.u = *(const uint4*)(K8b + (size_t)(s0 + 16 + l15) * 8);
    kA2.u = *(const uint4*)(K8b + (size_t)(s0 + 32 + l15) * 8);
    kA3.u = *(const uint4*)(K8b + (size_t)(s0 + 48 + l15) * 8);
  }
  if (l15 < 5) {
    vA0.u = *(const uint4*)(vplane + s0 +  0);
    vA1.u = *(const uint4*)(vplane + s0 + 32);
  }
  // fix quad offsets for prologue V load (match BODY's addressing)
  if (l15 < 5 && quad != 0) {
    vA0.u = *(const uint4*)(vplane + s0 +  0 + 8 * quad);
    vA1.u = *(const uint4*)(vplane + s0 + 32 + 8 * quad);
  }

  // it = 0: cur A, no PV yet; prefetch it=1 into B; write P(0) to even parity
  BODY(kA0, kA1, kA2, kA3, kB0, kB1, kB2, kB3, vB0, vB1,
       s0 + 64, false, true, PwE, PwE);
#pragma unroll
  for (int p = 0; p < 7; ++p) {
    const int it = 1 + 2 * p;
    // odd it: cur B, PV(it-1) with A's V + even-parity P; prefetch into A
    BODY(kB0, kB1, kB2, kB3, kA0, kA1, kA2, kA3, vA0, vA1,
         s0 + 64 * (it + 1), true, true, PwE, PwO);
    // even it+1: cur A, PV(it) with B's V + odd-parity P; prefetch into B
    BODY(kA0, kA1, kA2, kA3, kB0, kB1, kB2, kB3, vB0, vB1,
         s0 + 64 * (it + 2), true, true, PwO, PwE);
  }
  // it = 15: cur B, PV(14) with A's V + even-parity P; no prefetch
  BODY(kB0, kB1, kB2, kB3, kA0, kA1, kA2, kA3, vA0, vA1,
       0, true, false, PwE, PwO);
  // epilogue: PV(15) with B's V + odd-parity P
  {
    FU pa0, pa1;
    pa0.h = *(const f16x8*)(PwO + roff0);
    pa1.h = *(const f16x8*)(PwO + roff1);
    oacc = __builtin_amdgcn_mfma_f32_16x16x32_f16(pa0.h, vB0.h, oacc, 0, 0, 0);
    oacc = __builtin_amdgcn_mfma_f32_16x16x32_f16(pa1.h, vB1.h, oacc, 0, 0, 0);
  }

  // O D-layout: lane holds O[q=4*quad+reg][ch=l15]; ch0..4 = out, ch5 = l
  if (l15 < 6) {
    Ored[wv][4 * quad + 0][l15] = oacc.x;
    Ored[wv][4 * quad + 1][l15] = oacc.y;
    Ored[wv][4 * quad + 2][l15] = oacc.z;
    Ored[wv][4 * quad + 3][l15] = oacc.w;
  }
  __syncthreads();
  if (tid < 96) {
    const int q = tid / 6, comp = tid % 6;
    const float s = Ored[0][q][comp] + Ored[1][q][comp] +
                    Ored[2][q][comp] + Ored[3][q][comp];
    const int j = j0 + q;
    if (j < cb) {
      const int n = perm[j];
      ((float*)(wsb + PART_OFF))[((size_t)chunk * Nq + n) * 6 + comp] = s;
    }
  }
}

__global__ __launch_bounds__(256) void k3_final(
    const float* __restrict__ x, const float* __restrict__ gamma,
    const int* __restrict__ idx_b, const int* __restrict__ idx_h,
    const int* __restrict__ idx_w, float* __restrict__ y,
    const char* __restrict__ wsb) {
  const int n = blockIdx.x * 256 + threadIdx.x;   // grid exactly Nq
  const float* part = (const float*)(wsb + PART_OFF);
  float l = 0.f, o[5] = {0.f, 0.f, 0.f, 0.f, 0.f};
#pragma unroll
  for (int ch = 0; ch < SPLIT; ++ch) {
    const float* p = part + ((size_t)ch * Nq + n) * 6;
#pragma unroll
    for (int c = 0; c < 5; ++c) o[c] += p[c];
    l += p[5];
  }
  const float gsc = gamma[0] + 0.1f;
  const float inv = 1.0f / l;
  const int b = idx_b[n], h = idx_h[n], w = idx_w[n];
  const int s = h * Wc + w;
#pragma unroll
  for (int c = 0; c < 5; ++c) {
    const size_t off = (size_t)(b * 5 + c) * HWC + s;
    y[off] = fmaf(gsc, o[c] * inv, x[off]);   // duplicates write identical values
  }
}

extern "C" void kernel_launch(void* const* d_in, const int* in_sizes, int n_in,
                              void* d_out, int out_size, void* d_ws, size_t ws_size,
                              hipStream_t stream) {
  const float* x     = (const float*)d_in[0];
  const float* Wq    = (const float*)d_in[1];
  const float* bq    = (const float*)d_in[2];
  const float* Wk    = (const float*)d_in[3];
  const float* bk    = (const float*)d_in[4];
  const float* Wv    = (const float*)d_in[5];
  const float* bv    = (const float*)d_in[6];
  const float* gamma = (const float*)d_in[7];
  const int* idx_b   = (const int*)d_in[8];
  const int* idx_h   = (const int*)d_in[9];
  const int* idx_w   = (const int*)d_in[10];
  float* y  = (float*)d_out;
  char* wsb = (char*)d_ws;   // needs ~7.5 MB

  k1_prep<<<1033, 256, 0, stream>>>(x, Wq, bq, Wk, bk, Wv, bv,
                                    idx_b, idx_h, idx_w, y, wsb);
  k2_attn<<<dim3(SPLIT, Bc * TPB), 256, 0, stream>>>(wsb);
  k3_final<<<Nq / 256, 256, 0, stream>>>(x, gamma, idx_b, idx_h, idx_w, y, wsb);
}

// Round 2
// 108.614 us; speedup vs baseline: 1.1003x; 1.0921x over previous
//
#include <hip/hip_runtime.h>

// UNet_86406152061381: pixel-sampled self-attention, fp32 in/out, C=5.
// R12 = k2 q-tile grouping (G=4): each block now serves 64 queries (4
// 16-q tiles) per s-chunk, re-using each K/V fragment 4x. K/V cache-side
// read traffic drops 218 MB -> 55 MB (this was the real k2 floor; R11's
// latency-pipelining was neutral because the pipe was traffic-bound, not
// stall-bound). SPLIT 16->32 keeps ~4 waves/SIMD occupancy (s-traffic is
// independent of SPLIT). K stays register-ping-ponged (prefetched 4 steps
// ahead); V drops to a single set (reloaded 1 step before first use).
// P tile stays parity-ping-ponged in LDS by step parity (step = 4*it+g).
// MFMA flash k2: E' = K.Q^T via mfma_f32_16x16x32_f16 (bias in C), exp2 on
// VALU, P f16 via per-wave LDS, O = P.V via MFMA, l = ones-channel 5 of V.

constexpr int HWC = 256 * 256;   // 65536
constexpr int Bc  = 4;
constexpr int Nq  = 2048;
constexpr int Wc  = 256;

constexpr int QG    = 10;            // 64-q groups per b (cb<=640 proven)
constexpr int SPLIT = 32;            // s-chunks; chunk = 2048 s; wave = 512 s

constexpr float LOG2E = 1.4426950408889634f;
constexpr float BIAS2 = -14.0f * LOG2E;   // fixed softmax shift, base-2 domain
                                          // (-14: f16-P window, see R8 note)

// workspace layout (byte offsets, all 16B-aligned); total ~9 MB
constexpr size_t K8_BYTES  = (size_t)Bc * HWC * 8 * 2;   // f16[Bc][HWC][8]
constexpr size_t VT_BYTES  = (size_t)Bc * 5 * HWC * 2;   // f16[Bc][5][HWC]
constexpr size_t QP_BYTES  = (size_t)Nq * 8 * 2;         // f16[Nq][8]
constexpr size_t PART_BYTES = (size_t)SPLIT * Nq * 6 * 4;
constexpr size_t K8_OFF   = 0;
constexpr size_t VT_OFF   = K8_OFF + K8_BYTES;
constexpr size_t QP16_OFF = VT_OFF + VT_BYTES;
constexpr size_t PART_OFF = QP16_OFF + QP_BYTES;
constexpr size_t PERM_OFF = PART_OFF + PART_BYTES;       // int[Bc][Nq]
constexpr size_t CNT_OFF  = PERM_OFF + (size_t)Bc * Nq * 4;  // int[Bc]

typedef __attribute__((ext_vector_type(8))) _Float16 f16x8;
typedef __attribute__((ext_vector_type(4))) float f32x4;
union FU { uint4 u; f16x8 h; };

#if defined(__has_builtin)
#if __has_builtin(__builtin_amdgcn_exp2f)
#define EXP2F(x) __builtin_amdgcn_exp2f(x)
#endif
#endif
#ifndef EXP2F
#define EXP2F(x) exp2f(x)
#endif

__device__ inline unsigned pack2(float a, float b) {
  typedef __attribute__((ext_vector_type(2))) __fp16 fp16x2;
  union { fp16x2 h; unsigned u; } r;
  r.h = __builtin_amdgcn_cvt_pkrtz(a, b);
  return r.u;
}

// blocks 0..1023: K/V staging (f16) + y<-x copy.
// blocks 1024..1031: q_pix (scaled by LOG2E) -> f16 rows.
// block 1032: bucket queries by b (perm + cnt).
__global__ __launch_bounds__(256) void k1_prep(
    const float* __restrict__ x,
    const float* __restrict__ Wq, const float* __restrict__ bq,
    const float* __restrict__ Wk, const float* __restrict__ bk,
    const float* __restrict__ Wv, const float* __restrict__ bv,
    const int* __restrict__ idx_b, const int* __restrict__ idx_h,
    const int* __restrict__ idx_w,
    float* __restrict__ y, char* __restrict__ wsb) {
  const int tid = threadIdx.x;
  _Float16* K8   = (_Float16*)(wsb + K8_OFF);
  _Float16* VT   = (_Float16*)(wsb + VT_OFF);
  _Float16* QP16 = (_Float16*)(wsb + QP16_OFF);
  if (blockIdx.x >= 1024) {
    if (blockIdx.x == 1032) {
      __shared__ int lcnt[Bc];
      if (tid < Bc) lcnt[tid] = 0;
      __syncthreads();
      int* perm = (int*)(wsb + PERM_OFF);
#pragma unroll
      for (int qi = 0; qi < 8; ++qi) {
        const int n = qi * 256 + tid;            // Nq = 8*256 exactly
        const int b = idx_b[n];
        const int pos = atomicAdd(&lcnt[b], 1);  // order irrelevant
        perm[b * Nq + pos] = n;
      }
      __syncthreads();
      if (tid < Bc) ((int*)(wsb + CNT_OFF))[tid] = lcnt[tid];
      return;
    }
    // ---- query part: 8 blocks x 256 queries
    const int n = (blockIdx.x - 1024) * 256 + tid;
    const int b = idx_b[n];
    const int s = idx_h[n] * Wc + idx_w[n];
    float xv[5];
#pragma unroll
    for (int c = 0; c < 5; ++c) xv[c] = x[(size_t)(b * 5 + c) * HWC + s];
    float q[5];
#pragma unroll
    for (int o = 0; o < 5; ++o) {
      float t = bq[o];
#pragma unroll
      for (int c = 0; c < 5; ++c) t = fmaf(Wq[o * 5 + c], xv[c], t);
      q[o] = t * LOG2E;
    }
    uint4 row;
    row.x = pack2(q[0], q[1]);
    row.y = pack2(q[2], q[3]);
    row.z = pack2(q[4], 0.f);
    row.w = 0u;
    *(uint4*)(QP16 + (size_t)n * 8) = row;
    return;
  }
  // ---- staging: 1 pixel/thread
  const int gid = blockIdx.x * 256 + tid;      // 0..262143
  const int b   = gid >> 16;
  const int s   = gid & (HWC - 1);
  float xv[5];
#pragma unroll
  for (int c = 0; c < 5; ++c) {
    const size_t off = (size_t)(b * 5 + c) * HWC + s;
    xv[c] = x[off];
    y[off] = xv[c];
  }
  float kk[5], vv[5];
#pragma unroll
  for (int o = 0; o < 5; ++o) {
    kk[o] = bk[o];
    vv[o] = bv[o];
#pragma unroll
    for (int c = 0; c < 5; ++c) {
      kk[o] = fmaf(Wk[o * 5 + c], xv[c], kk[o]);
      vv[o] = fmaf(Wv[o * 5 + c], xv[c], vv[o]);
    }
  }
  uint4 krow;
  krow.x = pack2(kk[0], kk[1]);
  krow.y = pack2(kk[2], kk[3]);
  krow.z = pack2(kk[4], 0.f);
  krow.w = 0u;
  *(uint4*)(K8 + (size_t)(b * HWC + s) * 8) = krow;
#pragma unroll
  for (int c = 0; c < 5; ++c)
    VT[(size_t)(b * 5 + c) * HWC + s] = (_Float16)vv[c];
}

// grid (SPLIT=32, Bc*QG=40): blockIdx.x = chunk, blockIdx.y = (b, q-group).
// 4 waves/block, each wave owns 512 s of the chunk (8 iters x 4 q-tiles).
//
// STEP(it,g): E-MFMA(cur K, Q[g]) -> PV of previous step (ds_read prev-
// parity P x single-set V) -> [optional V reload / K prefetch] -> exp/pack
// -> ds_write cur-parity P. Step parity = g&1; P reads/writes never alias.
#define STEP(KC0, KC1, KC2, KC3, QF, DOPV, OACC, RPW, WPW,                    \
             DOLV, VBASE, DOLK, KD0, KD1, KD2, KD3, KBASE)                    \
  do {                                                                        \
    f32x4 e0 = __builtin_amdgcn_mfma_f32_16x16x32_f16(KC0.h, QF.h, bias, 0, 0, 0); \
    f32x4 e1 = __builtin_amdgcn_mfma_f32_16x16x32_f16(KC1.h, QF.h, bias, 0, 0, 0); \
    f32x4 e2 = __builtin_amdgcn_mfma_f32_16x16x32_f16(KC2.h, QF.h, bias, 0, 0, 0); \
    f32x4 e3 = __builtin_amdgcn_mfma_f32_16x16x32_f16(KC3.h, QF.h, bias, 0, 0, 0); \
    if (DOPV) {                                                               \
      FU pa0, pa1;                                                            \
      pa0.h = *(const f16x8*)((RPW) + roff0);                                 \
      pa1.h = *(const f16x8*)((RPW) + roff1);                                 \
      OACC = __builtin_amdgcn_mfma_f32_16x16x32_f16(pa0.h, v0.h, OACC, 0, 0, 0); \
      OACC = __builtin_amdgcn_mfma_f32_16x16x32_f16(pa1.h, v1.h, OACC, 0, 0, 0); \
    }                                                                         \
    if (DOLV) {                                                               \
      if (l15 < 5) {                                                          \
        v0.u = *(const uint4*)(vplane + (VBASE) +  0 + 8 * quad);             \
        v1.u = *(const uint4*)(vplane + (VBASE) + 32 + 8 * quad);             \
      }                                                                       \
    }                                                                         \
    if (DOLK) {                                                               \
      if (quad == 0) {                                                        \
        KD0.u = *(const uint4*)(K8b + (size_t)((KBASE) +  0 + l15) * 8);      \
        KD1.u = *(const uint4*)(K8b + (size_t)((KBASE) + 16 + l15) * 8);      \
        KD2.u = *(const uint4*)(K8b + (size_t)((KBASE) + 32 + l15) * 8);      \
        KD3.u = *(const uint4*)(K8b + (size_t)((KBASE) + 48 + l15) * 8);      \
      }                                                                       \
    }                                                                         \
    uint2 w0, w1, w2, w3;                                                     \
    w0.x = pack2(EXP2F(e0.x), EXP2F(e0.y)); w0.y = pack2(EXP2F(e0.z), EXP2F(e0.w)); \
    w1.x = pack2(EXP2F(e1.x), EXP2F(e1.y)); w1.y = pack2(EXP2F(e1.z), EXP2F(e1.w)); \
    w2.x = pack2(EXP2F(e2.x), EXP2F(e2.y)); w2.y = pack2(EXP2F(e2.z), EXP2F(e2.w)); \
    w3.x = pack2(EXP2F(e3.x), EXP2F(e3.y)); w3.y = pack2(EXP2F(e3.z), EXP2F(e3.w)); \
    *(uint2*)((WPW) + woff0) = w0;                                            \
    *(uint2*)((WPW) + woff1) = w1;                                            \
    *(uint2*)((WPW) + woff2) = w2;                                            \
    *(uint2*)((WPW) + woff3) = w3;                                            \
  } while (0)

__global__ __launch_bounds__(256, 4) void k2_attn(char* __restrict__ wsb) {
  const int chunk = blockIdx.x;
  const int tile  = blockIdx.y;
  const int bb    = tile / QG;
  const int tg    = tile % QG;
  const int cb    = ((const int*)(wsb + CNT_OFF))[bb];
  const int j0    = tg * 64;
  if (j0 >= cb) return;                   // padding group: whole block exits
  const int* perm = (const int*)(wsb + PERM_OFF) + bb * Nq;

  const int tid  = threadIdx.x;
  const int wv   = tid >> 6;
  const int lane = tid & 63;
  const int quad = lane >> 4;
  const int l15  = lane & 15;

  // P tile, parity ping-pong by step: [wave][parity][q=16][64].
  // Row = 64 halves (128 B). 8-byte group g of row l15 stored at
  // g ^ (2*(l15&7)): b64 writes / b128 reads 16B-aligned, conflict-free.
  __shared__ _Float16 Pbuf[4][2][16][64];
  __shared__ float    Ored[4][4][16][6];   // [wave][qtile][q][comp]

  const _Float16* K8b  = (const _Float16*)(wsb + K8_OFF) + (size_t)bb * HWC * 8;
  const _Float16* Vtb  = (const _Float16*)(wsb + VT_OFF) + (size_t)bb * 5 * HWC;
  const _Float16* QP16 = (const _Float16*)(wsb + QP16_OFF);

  _Float16* PwE = &Pbuf[wv][0][0][0];     // even-step parity (g even)
  _Float16* PwO = &Pbuf[wv][1][0][0];     // odd-step parity (g odd)
  const int swzg = 2 * (l15 & 7);          // group-unit swizzle for this row
  const int rowb = l15 << 6;               // row base in halves
  const int woff0 = rowb + (((0 * 4 + quad) ^ swzg) << 2);
  const int woff1 = rowb + (((1 * 4 + quad) ^ swzg) << 2);
  const int woff2 = rowb + (((2 * 4 + quad) ^ swzg) << 2);
  const int woff3 = rowb + (((3 * 4 + quad) ^ swzg) << 2);
  const int roff0 = rowb + (((0 + 2 * quad) ^ swzg) << 2);
  const int roff1 = rowb + (((8 + 2 * quad) ^ swzg) << 2);

  // Q B-fragments, one per 16-q tile (constant): quad0 lanes hold
  // Q[q=l15][c=0..7], rest 0.
  FU qf0, qf1, qf2, qf3;
  qf0.u = make_uint4(0u, 0u, 0u, 0u);
  qf1.u = qf0.u; qf2.u = qf0.u; qf3.u = qf0.u;
  if (quad == 0) {
#define QLOAD(QF, G)                                                          \
    do {                                                                      \
      const int jq = j0 + 16 * (G) + l15;                                     \
      const int n = (jq < cb) ? perm[jq] : 0;  /* invalid cols discarded */   \
      QF.u = *(const uint4*)(QP16 + (size_t)n * 8);                           \
    } while (0)
    QLOAD(qf0, 0); QLOAD(qf1, 1); QLOAD(qf2, 2); QLOAD(qf3, 3);
#undef QLOAD
  }
  // V B-fragment, single set: ch=l15<5 reloaded per s-iter (1 step before
  // first use); ch==5 = ones (denominator); other lanes stay 0.
  FU v0, v1;
  {
    const unsigned ones = (l15 == 5) ? 0x3C003C00u : 0u;
    v0.u = make_uint4(ones, ones, ones, ones);
    v1.u = v0.u;
  }
  // K A-fragments (ping-pong sets A/B, prefetched 4 steps ahead):
  // only quad0 lanes ever loaded; others stay 0.
  FU kA0, kA1, kA2, kA3, kB0, kB1, kB2, kB3;
  kA0.u = make_uint4(0u, 0u, 0u, 0u);
  kA1.u = kA0.u; kA2.u = kA0.u; kA3.u = kA0.u;
  kB0.u = kA0.u; kB1.u = kA0.u; kB2.u = kA0.u; kB3.u = kA0.u;

  const f32x4 bias = {BIAS2, BIAS2, BIAS2, BIAS2};
  f32x4 oacc0 = {0.f, 0.f, 0.f, 0.f};
  f32x4 oacc1 = oacc0, oacc2 = oacc0, oacc3 = oacc0;

  const _Float16* vplane = Vtb + (size_t)l15 * HWC;   // valid when l15<5

  const int s0w = chunk * (HWC / SPLIT) + wv * (HWC / SPLIT / 4);

  // prologue: K(0) -> A, V(0) -> v
  if (quad == 0) {
    kA0.u = *(const uint4*)(K8b + (size_t)(s0w +  0 + l15) * 8);
    kA1.u = *(const uint4*)(K8b + (size_t)(s0w + 16 + l15) * 8);
    kA2.u = *(const uint4*)(K8b + (size_t)(s0w + 32 + l15) * 8);
    kA3.u = *(const uint4*)(K8b + (size_t)(s0w + 48 + l15) * 8);
  }
  if (l15 < 5) {
    v0.u = *(const uint4*)(vplane + s0w +  0 + 8 * quad);
    v1.u = *(const uint4*)(vplane + s0w + 32 + 8 * quad);
  }

  // it0 (set A): g0 has no PV; prefetch K(1)->B
  STEP(kA0, kA1, kA2, kA3, qf0, false, oacc0, PwE, PwE,
       false, 0, true, kB0, kB1, kB2, kB3, s0w + 64);
  STEP(kA0, kA1, kA2, kA3, qf1, true, oacc0, PwE, PwO,
       false, 0, false, kB0, kB1, kB2, kB3, 0);
  STEP(kA0, kA1, kA2, kA3, qf2, true, oacc1, PwO, PwE,
       false, 0, false, kB0, kB1, kB2, kB3, 0);
  STEP(kA0, kA1, kA2, kA3, qf3, true, oacc2, PwE, PwO,
       false, 0, false, kB0, kB1, kB2, kB3, 0);

#pragma unroll
  for (int p = 0; p < 3; ++p) {
    const int ob = s0w + 64 * (2 * p + 1);   // odd-it base
    const int eb = s0w + 64 * (2 * p + 2);   // even-it base (also K prefetch @odd)
    const int nb = s0w + 64 * (2 * p + 3);   // K prefetch target @even
    // odd it (set B): g0 -> PV of prev-it g3 (V(it-1) still in v), then
    // reload v = V(it), prefetch K(it+1) -> A
    STEP(kB0, kB1, kB2, kB3, qf0, true, oacc3, PwO, PwE,
         true, ob, true, kA0, kA1, kA2, kA3, eb);
    STEP(kB0, kB1, kB2, kB3, qf1, true, oacc0, PwE, PwO,
         false, 0, false, kA0, kA1, kA2, kA3, 0);
    STEP(kB0, kB1, kB2, kB3, qf2, true, oacc1, PwO, PwE,
         false, 0, false, kA0, kA1, kA2, kA3, 0);
    STEP(kB0, kB1, kB2, kB3, qf3, true, oacc2, PwE, PwO,
         false, 0, false, kA0, kA1, kA2, kA3, 0);
    // even it (set A)
    STEP(kA0, kA1, kA2, kA3, qf0, true, oacc3, PwO, PwE,
         true, eb, true, kB0, kB1, kB2, kB3, nb);
    STEP(kA0, kA1, kA2, kA3, qf1, true, oacc0, PwE, PwO,
         false, 0, false, kB0, kB1, kB2, kB3, 0);
    STEP(kA0, kA1, kA2, kA3, qf2, true, oacc1, PwO, PwE,
         false, 0, false, kB0, kB1, kB2, kB3, 0);
    STEP(kA0, kA1, kA2, kA3, qf3, true, oacc2, PwE, PwO,
         false, 0, false, kB0, kB1, kB2, kB3, 0);
  }

  // it7 (set B): no K prefetch
  STEP(kB0, kB1, kB2, kB3, qf0, true, oacc3, PwO, PwE,
       true, s0w + 64 * 7, false, kA0, kA1, kA2, kA3, 0);
  STEP(kB0, kB1, kB2, kB3, qf1, true, oacc0, PwE, PwO,
       false, 0, false, kA0, kA1, kA2, kA3, 0);
  STEP(kB0, kB1, kB2, kB3, qf2, true, oacc1, PwO, PwE,
       false, 0, false, kA0, kA1, kA2, kA3, 0);
  STEP(kB0, kB1, kB2, kB3, qf3, true, oacc2, PwE, PwO,
       false, 0, false, kA0, kA1, kA2, kA3, 0);
  // epilogue: PV of (it7,g3) from odd parity, V(7) still in v
  {
    FU pa0, pa1;
    pa0.h = *(const f16x8*)(PwO + roff0);
    pa1.h = *(const f16x8*)(PwO + roff1);
    oacc3 = __builtin_amdgcn_mfma_f32_16x16x32_f16(pa0.h, v0.h, oacc3, 0, 0, 0);
    oacc3 = __builtin_amdgcn_mfma_f32_16x16x32_f16(pa1.h, v1.h, oacc3, 0, 0, 0);
  }

  // O D-layout: lane holds O[q=4*quad+reg][ch=l15]; ch0..4 = out, ch5 = l
  if (l15 < 6) {
#define OSTORE(G, OA)                                                         \
    do {                                                                      \
      Ored[wv][G][4 * quad + 0][l15] = OA.x;                                  \
      Ored[wv][G][4 * quad + 1][l15] = OA.y;                                  \
      Ored[wv][G][4 * quad + 2][l15] = OA.z;                                  \
      Ored[wv][G][4 * quad + 3][l15] = OA.w;                                  \
    } while (0)
    OSTORE(0, oacc0); OSTORE(1, oacc1); OSTORE(2, oacc2); OSTORE(3, oacc3);
#undef OSTORE
  }
  __syncthreads();
  for (int o = tid; o < 64 * 6; o += 256) {
    const int q64 = o / 6, comp = o % 6;
    const int g = q64 >> 4, q16 = q64 & 15;
    const float s = Ored[0][g][q16][comp] + Ored[1][g][q16][comp] +
                    Ored[2][g][q16][comp] + Ored[3][g][q16][comp];
    const int j = j0 + q64;
    if (j < cb) {
      const int n = perm[j];
      ((float*)(wsb + PART_OFF))[((size_t)chunk * Nq + n) * 6 + comp] = s;
    }
  }
}

__global__ __launch_bounds__(256) void k3_final(
    const float* __restrict__ x, const float* __restrict__ gamma,
    const int* __restrict__ idx_b, const int* __restrict__ idx_h,
    const int* __restrict__ idx_w, float* __restrict__ y,
    const char* __restrict__ wsb) {
  const int n = blockIdx.x * 256 + threadIdx.x;   // grid exactly Nq
  const float* part = (const float*)(wsb + PART_OFF);
  float l = 0.f, o[5] = {0.f, 0.f, 0.f, 0.f, 0.f};
#pragma unroll
  for (int ch = 0; ch < SPLIT; ++ch) {
    const float* p = part + ((size_t)ch * Nq + n) * 6;
#pragma unroll
    for (int c = 0; c < 5; ++c) o[c] += p[c];
    l += p[5];
  }
  const float gsc = gamma[0] + 0.1f;
  const float inv = 1.0f / l;
  const int b = idx_b[n], h = idx_h[n], w = idx_w[n];
  const int s = h * Wc + w;
#pragma unroll
  for (int c = 0; c < 5; ++c) {
    const size_t off = (size_t)(b * 5 + c) * HWC + s;
    y[off] = fmaf(gsc, o[c] * inv, x[off]);   // duplicates write identical values
  }
}

extern "C" void kernel_launch(void* const* d_in, const int* in_sizes, int n_in,
                              void* d_out, int out_size, void* d_ws, size_t ws_size,
                              hipStream_t stream) {
  const float* x     = (const float*)d_in[0];
  const float* Wq    = (const float*)d_in[1];
  const float* bq    = (const float*)d_in[2];
  const float* Wk    = (const float*)d_in[3];
  const float* bk    = (const float*)d_in[4];
  const float* Wv    = (const float*)d_in[5];
  const float* bv    = (const float*)d_in[6];
  const float* gamma = (const float*)d_in[7];
  const int* idx_b   = (const int*)d_in[8];
  const int* idx_h   = (const int*)d_in[9];
  const int* idx_w   = (const int*)d_in[10];
  float* y  = (float*)d_out;
  char* wsb = (char*)d_ws;   // needs ~9 MB

  k1_prep<<<1033, 256, 0, stream>>>(x, Wq, bq, Wk, bk, Wv, bv,
                                    idx_b, idx_h, idx_w, y, wsb);
  k2_attn<<<dim3(SPLIT, Bc * QG), 256, 0, stream>>>(wsb);
  k3_final<<<Nq / 256, 256, 0, stream>>>(x, gamma, idx_b, idx_h, idx_w, y, wsb);
}

// Round 3
// 108.032 us; speedup vs baseline: 1.1063x; 1.0054x over previous
//
#include <hip/hip_runtime.h>

// UNet_86406152061381: pixel-sampled self-attention, fp32 in/out, C=5.
// R13 = R12 (k2 untouched: G=4 q-grouping, SPLIT=32, K reg-ping-pong,
// P parity LDS ping-pong) + vectorized small kernels:
//   * k1 staging: 4 px/thread, float4 x-loads / y-stores, uint2 VT stores
//     (grid 1033 -> 265 blocks); identical FMA order -> bit-identical.
//   * k3: 3x float2 loads per partial row (was 6 scalars), 32 blocks x 64
//     threads (was 8 x 256) -> 4x the CUs on a latency-bound reduce.
// Decomposition after R12: 2x 256MiB harness poison fills ~81 us (fixed),
// k2 ~13 us (VALU-floor ~10: 134M exp2 @ quarter rate), k1+k3+gaps ~13 us.
// MFMA flash k2: E' = K.Q^T via mfma_f32_16x16x32_f16 (bias in C), exp2 on
// VALU, P f16 via per-wave LDS, O = P.V via MFMA, l = ones-channel 5 of V.

constexpr int HWC = 256 * 256;   // 65536
constexpr int Bc  = 4;
constexpr int Nq  = 2048;
constexpr int Wc  = 256;

constexpr int QG    = 10;            // 64-q groups per b (cb<=640 proven)
constexpr int SPLIT = 32;            // s-chunks; chunk = 2048 s; wave = 512 s

constexpr float LOG2E = 1.4426950408889634f;
constexpr float BIAS2 = -14.0f * LOG2E;   // fixed softmax shift, base-2 domain
                                          // (-14: f16-P window, see R8 note)

// workspace layout (byte offsets, all 16B-aligned); total ~9 MB
constexpr size_t K8_BYTES  = (size_t)Bc * HWC * 8 * 2;   // f16[Bc][HWC][8]
constexpr size_t VT_BYTES  = (size_t)Bc * 5 * HWC * 2;   // f16[Bc][5][HWC]
constexpr size_t QP_BYTES  = (size_t)Nq * 8 * 2;         // f16[Nq][8]
constexpr size_t PART_BYTES = (size_t)SPLIT * Nq * 6 * 4;
constexpr size_t K8_OFF   = 0;
constexpr size_t VT_OFF   = K8_OFF + K8_BYTES;
constexpr size_t QP16_OFF = VT_OFF + VT_BYTES;
constexpr size_t PART_OFF = QP16_OFF + QP_BYTES;
constexpr size_t PERM_OFF = PART_OFF + PART_BYTES;       // int[Bc][Nq]
constexpr size_t CNT_OFF  = PERM_OFF + (size_t)Bc * Nq * 4;  // int[Bc]

typedef __attribute__((ext_vector_type(8))) _Float16 f16x8;
typedef __attribute__((ext_vector_type(4))) float f32x4;
union FU { uint4 u; f16x8 h; };

#if defined(__has_builtin)
#if __has_builtin(__builtin_amdgcn_exp2f)
#define EXP2F(x) __builtin_amdgcn_exp2f(x)
#endif
#endif
#ifndef EXP2F
#define EXP2F(x) exp2f(x)
#endif

__device__ inline unsigned pack2(float a, float b) {
  typedef __attribute__((ext_vector_type(2))) __fp16 fp16x2;
  union { fp16x2 h; unsigned u; } r;
  r.h = __builtin_amdgcn_cvt_pkrtz(a, b);
  return r.u;
}

// blocks 0..255: K/V staging (f16) + y<-x copy, 4 px/thread (vectorized).
// blocks 256..263: q_pix (scaled by LOG2E) -> f16 rows.
// block 264: bucket queries by b (perm + cnt).
__global__ __launch_bounds__(256) void k1_prep(
    const float* __restrict__ x,
    const float* __restrict__ Wq, const float* __restrict__ bq,
    const float* __restrict__ Wk, const float* __restrict__ bk,
    const float* __restrict__ Wv, const float* __restrict__ bv,
    const int* __restrict__ idx_b, const int* __restrict__ idx_h,
    const int* __restrict__ idx_w,
    float* __restrict__ y, char* __restrict__ wsb) {
  const int tid = threadIdx.x;
  _Float16* K8   = (_Float16*)(wsb + K8_OFF);
  _Float16* VT   = (_Float16*)(wsb + VT_OFF);
  _Float16* QP16 = (_Float16*)(wsb + QP16_OFF);
  if (blockIdx.x >= 256) {
    if (blockIdx.x == 264) {
      __shared__ int lcnt[Bc];
      if (tid < Bc) lcnt[tid] = 0;
      __syncthreads();
      int* perm = (int*)(wsb + PERM_OFF);
#pragma unroll
      for (int qi = 0; qi < 8; ++qi) {
        const int n = qi * 256 + tid;            // Nq = 8*256 exactly
        const int b = idx_b[n];
        const int pos = atomicAdd(&lcnt[b], 1);  // order irrelevant
        perm[b * Nq + pos] = n;
      }
      __syncthreads();
      if (tid < Bc) ((int*)(wsb + CNT_OFF))[tid] = lcnt[tid];
      return;
    }
    // ---- query part: 8 blocks x 256 queries
    const int n = (blockIdx.x - 256) * 256 + tid;
    const int b = idx_b[n];
    const int s = idx_h[n] * Wc + idx_w[n];
    float xv[5];
#pragma unroll
    for (int c = 0; c < 5; ++c) xv[c] = x[(size_t)(b * 5 + c) * HWC + s];
    float q[5];
#pragma unroll
    for (int o = 0; o < 5; ++o) {
      float t = bq[o];
#pragma unroll
      for (int c = 0; c < 5; ++c) t = fmaf(Wq[o * 5 + c], xv[c], t);
      q[o] = t * LOG2E;
    }
    uint4 row;
    row.x = pack2(q[0], q[1]);
    row.y = pack2(q[2], q[3]);
    row.z = pack2(q[4], 0.f);
    row.w = 0u;
    *(uint4*)(QP16 + (size_t)n * 8) = row;
    return;
  }
  // ---- staging: 4 pixels/thread, float4-vectorized
  const int gid = blockIdx.x * 256 + tid;      // 0..65535
  const int p0  = gid << 2;                    // first pixel of this thread
  const int b   = p0 >> 16;
  const int s   = p0 & (HWC - 1);              // multiple of 4 -> 16B aligned
  float4 xv[5];
#pragma unroll
  for (int c = 0; c < 5; ++c) {
    const size_t off = (size_t)(b * 5 + c) * HWC + s;
    xv[c] = *(const float4*)(x + off);
    *(float4*)(y + off) = xv[c];
  }
  float vvv[4][5];
#pragma unroll
  for (int j = 0; j < 4; ++j) {
    float xs[5];
#pragma unroll
    for (int c = 0; c < 5; ++c) xs[c] = ((const float*)&xv[c])[j];
    float kk[5];
#pragma unroll
    for (int o = 0; o < 5; ++o) {
      kk[o] = bk[o];
      float vv = bv[o];
#pragma unroll
      for (int c = 0; c < 5; ++c) {
        kk[o] = fmaf(Wk[o * 5 + c], xs[c], kk[o]);
        vv    = fmaf(Wv[o * 5 + c], xs[c], vv);
      }
      vvv[j][o] = vv;
    }
    uint4 krow;
    krow.x = pack2(kk[0], kk[1]);
    krow.y = pack2(kk[2], kk[3]);
    krow.z = pack2(kk[4], 0.f);
    krow.w = 0u;
    *(uint4*)(K8 + (size_t)(b * HWC + s + j) * 8) = krow;
  }
#pragma unroll
  for (int c = 0; c < 5; ++c) {
    uint2 t;
    t.x = pack2(vvv[0][c], vvv[1][c]);
    t.y = pack2(vvv[2][c], vvv[3][c]);
    *(uint2*)(VT + (size_t)(b * 5 + c) * HWC + s) = t;   // 8B-aligned
  }
}

// grid (SPLIT=32, Bc*QG=40): blockIdx.x = chunk, blockIdx.y = (b, q-group).
// 4 waves/block, each wave owns 512 s of the chunk (8 iters x 4 q-tiles).
//
// STEP(it,g): E-MFMA(cur K, Q[g]) -> PV of previous step (ds_read prev-
// parity P x single-set V) -> [optional V reload / K prefetch] -> exp/pack
// -> ds_write cur-parity P. Step parity = g&1; P reads/writes never alias.
#define STEP(KC0, KC1, KC2, KC3, QF, DOPV, OACC, RPW, WPW,                    \
             DOLV, VBASE, DOLK, KD0, KD1, KD2, KD3, KBASE)                    \
  do {                                                                        \
    f32x4 e0 = __builtin_amdgcn_mfma_f32_16x16x32_f16(KC0.h, QF.h, bias, 0, 0, 0); \
    f32x4 e1 = __builtin_amdgcn_mfma_f32_16x16x32_f16(KC1.h, QF.h, bias, 0, 0, 0); \
    f32x4 e2 = __builtin_amdgcn_mfma_f32_16x16x32_f16(KC2.h, QF.h, bias, 0, 0, 0); \
    f32x4 e3 = __builtin_amdgcn_mfma_f32_16x16x32_f16(KC3.h, QF.h, bias, 0, 0, 0); \
    if (DOPV) {                                                               \
      FU pa0, pa1;                                                            \
      pa0.h = *(const f16x8*)((RPW) + roff0);                                 \
      pa1.h = *(const f16x8*)((RPW) + roff1);                                 \
      OACC = __builtin_amdgcn_mfma_f32_16x16x32_f16(pa0.h, v0.h, OACC, 0, 0, 0); \
      OACC = __builtin_amdgcn_mfma_f32_16x16x32_f16(pa1.h, v1.h, OACC, 0, 0, 0); \
    }                                                                         \
    if (DOLV) {                                                               \
      if (l15 < 5) {                                                          \
        v0.u = *(const uint4*)(vplane + (VBASE) +  0 + 8 * quad);             \
        v1.u = *(const uint4*)(vplane + (VBASE) + 32 + 8 * quad);             \
      }                                                                       \
    }                                                                         \
    if (DOLK) {                                                               \
      if (quad == 0) {                                                        \
        KD0.u = *(const uint4*)(K8b + (size_t)((KBASE) +  0 + l15) * 8);      \
        KD1.u = *(const uint4*)(K8b + (size_t)((KBASE) + 16 + l15) * 8);      \
        KD2.u = *(const uint4*)(K8b + (size_t)((KBASE) + 32 + l15) * 8);      \
        KD3.u = *(const uint4*)(K8b + (size_t)((KBASE) + 48 + l15) * 8);      \
      }                                                                       \
    }                                                                         \
    uint2 w0, w1, w2, w3;                                                     \
    w0.x = pack2(EXP2F(e0.x), EXP2F(e0.y)); w0.y = pack2(EXP2F(e0.z), EXP2F(e0.w)); \
    w1.x = pack2(EXP2F(e1.x), EXP2F(e1.y)); w1.y = pack2(EXP2F(e1.z), EXP2F(e1.w)); \
    w2.x = pack2(EXP2F(e2.x), EXP2F(e2.y)); w2.y = pack2(EXP2F(e2.z), EXP2F(e2.w)); \
    w3.x = pack2(EXP2F(e3.x), EXP2F(e3.y)); w3.y = pack2(EXP2F(e3.z), EXP2F(e3.w)); \
    *(uint2*)((WPW) + woff0) = w0;                                            \
    *(uint2*)((WPW) + woff1) = w1;                                            \
    *(uint2*)((WPW) + woff2) = w2;                                            \
    *(uint2*)((WPW) + woff3) = w3;                                            \
  } while (0)

__global__ __launch_bounds__(256, 4) void k2_attn(char* __restrict__ wsb) {
  const int chunk = blockIdx.x;
  const int tile  = blockIdx.y;
  const int bb    = tile / QG;
  const int tg    = tile % QG;
  const int cb    = ((const int*)(wsb + CNT_OFF))[bb];
  const int j0    = tg * 64;
  if (j0 >= cb) return;                   // padding group: whole block exits
  const int* perm = (const int*)(wsb + PERM_OFF) + bb * Nq;

  const int tid  = threadIdx.x;
  const int wv   = tid >> 6;
  const int lane = tid & 63;
  const int quad = lane >> 4;
  const int l15  = lane & 15;

  // P tile, parity ping-pong by step: [wave][parity][q=16][64].
  // Row = 64 halves (128 B). 8-byte group g of row l15 stored at
  // g ^ (2*(l15&7)): b64 writes / b128 reads 16B-aligned, conflict-free.
  __shared__ _Float16 Pbuf[4][2][16][64];
  __shared__ float    Ored[4][4][16][6];   // [wave][qtile][q][comp]

  const _Float16* K8b  = (const _Float16*)(wsb + K8_OFF) + (size_t)bb * HWC * 8;
  const _Float16* Vtb  = (const _Float16*)(wsb + VT_OFF) + (size_t)bb * 5 * HWC;
  const _Float16* QP16 = (const _Float16*)(wsb + QP16_OFF);

  _Float16* PwE = &Pbuf[wv][0][0][0];     // even-step parity (g even)
  _Float16* PwO = &Pbuf[wv][1][0][0];     // odd-step parity (g odd)
  const int swzg = 2 * (l15 & 7);          // group-unit swizzle for this row
  const int rowb = l15 << 6;               // row base in halves
  const int woff0 = rowb + (((0 * 4 + quad) ^ swzg) << 2);
  const int woff1 = rowb + (((1 * 4 + quad) ^ swzg) << 2);
  const int woff2 = rowb + (((2 * 4 + quad) ^ swzg) << 2);
  const int woff3 = rowb + (((3 * 4 + quad) ^ swzg) << 2);
  const int roff0 = rowb + (((0 + 2 * quad) ^ swzg) << 2);
  const int roff1 = rowb + (((8 + 2 * quad) ^ swzg) << 2);

  // Q B-fragments, one per 16-q tile (constant): quad0 lanes hold
  // Q[q=l15][c=0..7], rest 0.
  FU qf0, qf1, qf2, qf3;
  qf0.u = make_uint4(0u, 0u, 0u, 0u);
  qf1.u = qf0.u; qf2.u = qf0.u; qf3.u = qf0.u;
  if (quad == 0) {
#define QLOAD(QF, G)                                                          \
    do {                                                                      \
      const int jq = j0 + 16 * (G) + l15;                                     \
      const int n = (jq < cb) ? perm[jq] : 0;  /* invalid cols discarded */   \
      QF.u = *(const uint4*)(QP16 + (size_t)n * 8);                           \
    } while (0)
    QLOAD(qf0, 0); QLOAD(qf1, 1); QLOAD(qf2, 2); QLOAD(qf3, 3);
#undef QLOAD
  }
  // V B-fragment, single set: ch=l15<5 reloaded per s-iter (1 step before
  // first use); ch==5 = ones (denominator); other lanes stay 0.
  FU v0, v1;
  {
    const unsigned ones = (l15 == 5) ? 0x3C003C00u : 0u;
    v0.u = make_uint4(ones, ones, ones, ones);
    v1.u = v0.u;
  }
  // K A-fragments (ping-pong sets A/B, prefetched 4 steps ahead):
  // only quad0 lanes ever loaded; others stay 0.
  FU kA0, kA1, kA2, kA3, kB0, kB1, kB2, kB3;
  kA0.u = make_uint4(0u, 0u, 0u, 0u);
  kA1.u = kA0.u; kA2.u = kA0.u; kA3.u = kA0.u;
  kB0.u = kA0.u; kB1.u = kA0.u; kB2.u = kA0.u; kB3.u = kA0.u;

  const f32x4 bias = {BIAS2, BIAS2, BIAS2, BIAS2};
  f32x4 oacc0 = {0.f, 0.f, 0.f, 0.f};
  f32x4 oacc1 = oacc0, oacc2 = oacc0, oacc3 = oacc0;

  const _Float16* vplane = Vtb + (size_t)l15 * HWC;   // valid when l15<5

  const int s0w = chunk * (HWC / SPLIT) + wv * (HWC / SPLIT / 4);

  // prologue: K(0) -> A, V(0) -> v
  if (quad == 0) {
    kA0.u = *(const uint4*)(K8b + (size_t)(s0w +  0 + l15) * 8);
    kA1.u = *(const uint4*)(K8b + (size_t)(s0w + 16 + l15) * 8);
    kA2.u = *(const uint4*)(K8b + (size_t)(s0w + 32 + l15) * 8);
    kA3.u = *(const uint4*)(K8b + (size_t)(s0w + 48 + l15) * 8);
  }
  if (l15 < 5) {
    v0.u = *(const uint4*)(vplane + s0w +  0 + 8 * quad);
    v1.u = *(const uint4*)(vplane + s0w + 32 + 8 * quad);
  }

  // it0 (set A): g0 has no PV; prefetch K(1)->B
  STEP(kA0, kA1, kA2, kA3, qf0, false, oacc0, PwE, PwE,
       false, 0, true, kB0, kB1, kB2, kB3, s0w + 64);
  STEP(kA0, kA1, kA2, kA3, qf1, true, oacc0, PwE, PwO,
       false, 0, false, kB0, kB1, kB2, kB3, 0);
  STEP(kA0, kA1, kA2, kA3, qf2, true, oacc1, PwO, PwE,
       false, 0, false, kB0, kB1, kB2, kB3, 0);
  STEP(kA0, kA1, kA2, kA3, qf3, true, oacc2, PwE, PwO,
       false, 0, false, kB0, kB1, kB2, kB3, 0);

#pragma unroll
  for (int p = 0; p < 3; ++p) {
    const int ob = s0w + 64 * (2 * p + 1);   // odd-it base
    const int eb = s0w + 64 * (2 * p + 2);   // even-it base (also K prefetch @odd)
    const int nb = s0w + 64 * (2 * p + 3);   // K prefetch target @even
    // odd it (set B): g0 -> PV of prev-it g3 (V(it-1) still in v), then
    // reload v = V(it), prefetch K(it+1) -> A
    STEP(kB0, kB1, kB2, kB3, qf0, true, oacc3, PwO, PwE,
         true, ob, true, kA0, kA1, kA2, kA3, eb);
    STEP(kB0, kB1, kB2, kB3, qf1, true, oacc0, PwE, PwO,
         false, 0, false, kA0, kA1, kA2, kA3, 0);
    STEP(kB0, kB1, kB2, kB3, qf2, true, oacc1, PwO, PwE,
         false, 0, false, kA0, kA1, kA2, kA3, 0);
    STEP(kB0, kB1, kB2, kB3, qf3, true, oacc2, PwE, PwO,
         false, 0, false, kA0, kA1, kA2, kA3, 0);
    // even it (set A)
    STEP(kA0, kA1, kA2, kA3, qf0, true, oacc3, PwO, PwE,
         true, eb, true, kB0, kB1, kB2, kB3, nb);
    STEP(kA0, kA1, kA2, kA3, qf1, true, oacc0, PwE, PwO,
         false, 0, false, kB0, kB1, kB2, kB3, 0);
    STEP(kA0, kA1, kA2, kA3, qf2, true, oacc1, PwO, PwE,
         false, 0, false, kB0, kB1, kB2, kB3, 0);
    STEP(kA0, kA1, kA2, kA3, qf3, true, oacc2, PwE, PwO,
         false, 0, false, kB0, kB1, kB2, kB3, 0);
  }

  // it7 (set B): no K prefetch
  STEP(kB0, kB1, kB2, kB3, qf0, true, oacc3, PwO, PwE,
       true, s0w + 64 * 7, false, kA0, kA1, kA2, kA3, 0);
  STEP(kB0, kB1, kB2, kB3, qf1, true, oacc0, PwE, PwO,
       false, 0, false, kA0, kA1, kA2, kA3, 0);
  STEP(kB0, kB1, kB2, kB3, qf2, true, oacc1, PwO, PwE,
       false, 0, false, kA0, kA1, kA2, kA3, 0);
  STEP(kB0, kB1, kB2, kB3, qf3, true, oacc2, PwE, PwO,
       false, 0, false, kA0, kA1, kA2, kA3, 0);
  // epilogue: PV of (it7,g3) from odd parity, V(7) still in v
  {
    FU pa0, pa1;
    pa0.h = *(const f16x8*)(PwO + roff0);
    pa1.h = *(const f16x8*)(PwO + roff1);
    oacc3 = __builtin_amdgcn_mfma_f32_16x16x32_f16(pa0.h, v0.h, oacc3, 0, 0, 0);
    oacc3 = __builtin_amdgcn_mfma_f32_16x16x32_f16(pa1.h, v1.h, oacc3, 0, 0, 0);
  }

  // O D-layout: lane holds O[q=4*quad+reg][ch=l15]; ch0..4 = out, ch5 = l
  if (l15 < 6) {
#define OSTORE(G, OA)                                                         \
    do {                                                                      \
      Ored[wv][G][4 * quad + 0][l15] = OA.x;                                  \
      Ored[wv][G][4 * quad + 1][l15] = OA.y;                                  \
      Ored[wv][G][4 * quad + 2][l15] = OA.z;                                  \
      Ored[wv][G][4 * quad + 3][l15] = OA.w;                                  \
    } while (0)
    OSTORE(0, oacc0); OSTORE(1, oacc1); OSTORE(2, oacc2); OSTORE(3, oacc3);
#undef OSTORE
  }
  __syncthreads();
  for (int o = tid; o < 64 * 6; o += 256) {
    const int q64 = o / 6, comp = o % 6;
    const int g = q64 >> 4, q16 = q64 & 15;
    const float s = Ored[0][g][q16][comp] + Ored[1][g][q16][comp] +
                    Ored[2][g][q16][comp] + Ored[3][g][q16][comp];
    const int j = j0 + q64;
    if (j < cb) {
      const int n = perm[j];
      ((float*)(wsb + PART_OFF))[((size_t)chunk * Nq + n) * 6 + comp] = s;
    }
  }
}

__global__ __launch_bounds__(64) void k3_final(
    const float* __restrict__ x, const float* __restrict__ gamma,
    const int* __restrict__ idx_b, const int* __restrict__ idx_h,
    const int* __restrict__ idx_w, float* __restrict__ y,
    const char* __restrict__ wsb) {
  const int n = blockIdx.x * 64 + threadIdx.x;   // grid exactly Nq (32x64)
  const float* part = (const float*)(wsb + PART_OFF);
  float l = 0.f, o[5] = {0.f, 0.f, 0.f, 0.f, 0.f};
#pragma unroll
  for (int ch = 0; ch < SPLIT; ++ch) {
    const float* p = part + ((size_t)ch * Nq + n) * 6;   // 24B row, 8B-aligned
    const float2 a  = *(const float2*)(p + 0);
    const float2 b2 = *(const float2*)(p + 2);
    const float2 c2 = *(const float2*)(p + 4);
    o[0] += a.x;  o[1] += a.y;
    o[2] += b2.x; o[3] += b2.y;
    o[4] += c2.x; l    += c2.y;
  }
  const float gsc = gamma[0] + 0.1f;
  const float inv = 1.0f / l;
  const int b = idx_b[n], h = idx_h[n], w = idx_w[n];
  const int s = h * Wc + w;
#pragma unroll
  for (int c = 0; c < 5; ++c) {
    const size_t off = (size_t)(b * 5 + c) * HWC + s;
    y[off] = fmaf(gsc, o[c] * inv, x[off]);   // duplicates write identical values
  }
}

extern "C" void kernel_launch(void* const* d_in, const int* in_sizes, int n_in,
                              void* d_out, int out_size, void* d_ws, size_t ws_size,
                              hipStream_t stream) {
  const float* x     = (const float*)d_in[0];
  const float* Wq    = (const float*)d_in[1];
  const float* bq    = (const float*)d_in[2];
  const float* Wk    = (const float*)d_in[3];
  const float* bk    = (const float*)d_in[4];
  const float* Wv    = (const float*)d_in[5];
  const float* bv    = (const float*)d_in[6];
  const float* gamma = (const float*)d_in[7];
  const int* idx_b   = (const int*)d_in[8];
  const int* idx_h   = (const int*)d_in[9];
  const int* idx_w   = (const int*)d_in[10];
  float* y  = (float*)d_out;
  char* wsb = (char*)d_ws;   // needs ~9 MB

  k1_prep<<<265, 256, 0, stream>>>(x, Wq, bq, Wk, bk, Wv, bv,
                                   idx_b, idx_h, idx_w, y, wsb);
  k2_attn<<<dim3(SPLIT, Bc * QG), 256, 0, stream>>>(wsb);
  k3_final<<<Nq / 64, 64, 0, stream>>>(x, gamma, idx_b, idx_h, idx_w, y, wsb);
}